// Round 10
// baseline (317.965 us; speedup 1.0000x reference)
//
#include <hip/hip_runtime.h>

#define N_NODES 50000
#define N_EDGES 320000
#define IN_FEAT 128
#define HIDDEN  256
#define NCLS    40
#define BN_EPS  1e-5f

#define SCAN_B  256
#define SCAN_NB ((N_NODES + SCAN_B - 1) / SCAN_B)   // 196
#define GNB     (N_NODES / 16)                      // 3125 blocks, 16 nodes each

// prep kernel partition
#define PREP_HIST_NB  (N_EDGES / 256)               // 1250
#define PREP_CVT_NB   (N_NODES * IN_FEAT / 8 / 256) // 3125
#define PREP_PACK_NB  54                            // 216 wave-units / 4

typedef __attribute__((ext_vector_type(8))) short bf16x8;
typedef __attribute__((ext_vector_type(4))) float f32x4;
typedef __attribute__((ext_vector_type(8))) unsigned short ushort8;

__device__ __forceinline__ unsigned short f2bf(float f) {
    union { float f; unsigned u; } a; a.f = f;
    unsigned r = a.u + 0x7fff + ((a.u >> 16) & 1);   // RNE
    return (unsigned short)(r >> 16);
}
__device__ __forceinline__ float bf2f(unsigned short u) {
    union { unsigned u; float f; } a; a.u = ((unsigned)u) << 16;
    return a.f;
}

__device__ __forceinline__ void packB_unit(const float* __restrict__ W,
                                           unsigned short* __restrict__ Bp,
                                           int nt, int kt, int nkt, int M, int lane) {
    const int n = nt * 16 + (lane & 15);
    const int kb = kt * 32 + (lane >> 4) * 8;
    unsigned short* dst = Bp + (((size_t)nt * nkt + kt) * 64 + lane) * 8;
#pragma unroll
    for (int j = 0; j < 8; j++)
        dst[j] = (n < M) ? f2bf(W[(size_t)(kb + j) * M + n]) : (unsigned short)0;
}

// ---------------- merged prep: hist + x cast + W packs ----------------
__global__ __launch_bounds__(256) void k_prep(const int* __restrict__ e_dst,
                                              int* __restrict__ counts,
                                              const float* __restrict__ x,
                                              ushort8* __restrict__ Xb,
                                              const float* __restrict__ W1,
                                              const float* __restrict__ W2,
                                              const float* __restrict__ W3,
                                              unsigned short* __restrict__ W1p,
                                              unsigned short* __restrict__ W2p,
                                              unsigned short* __restrict__ W3p) {
    const int b = blockIdx.x;
    const int tid = threadIdx.x;
    if (b < PREP_HIST_NB) {
        const int e = b * 256 + tid;                  // 1250*256 == N_EDGES
        atomicAdd(&counts[e_dst[e]], 1);
    } else if (b < PREP_HIST_NB + PREP_CVT_NB) {
        const int i = (b - PREP_HIST_NB) * 256 + tid; // exact cover
        float4 a = *(const float4*)(x + (size_t)i * 8);
        float4 c = *(const float4*)(x + (size_t)i * 8 + 4);
        ushort8 o = {f2bf(a.x), f2bf(a.y), f2bf(a.z), f2bf(a.w),
                     f2bf(c.x), f2bf(c.y), f2bf(c.z), f2bf(c.w)};
        Xb[i] = o;
    } else {
        const int wave = tid >> 6, lane = tid & 63;
        const int u = (b - PREP_HIST_NB - PREP_CVT_NB) * 4 + wave;  // 0..215
        if (u < 64) {
            packB_unit(W1, W1p, u >> 2, u & 3, 4, HIDDEN, lane);
        } else if (u < 192) {
            const int v = u - 64;
            packB_unit(W2, W2p, v >> 3, v & 7, 8, HIDDEN, lane);
        } else {
            const int v = u - 192;
            packB_unit(W3, W3p, v >> 3, v & 7, 8, NCLS, lane);
        }
    }
}

// ---------------- CSR scan ----------------
__global__ __launch_bounds__(SCAN_B) void k_scan_local(const int* __restrict__ counts,
                                                       int* __restrict__ rowp,
                                                       int* __restrict__ partials) {
    __shared__ int s[SCAN_B];
    const int tid = threadIdx.x;
    const int i = blockIdx.x * SCAN_B + tid;
    int v = (i < N_NODES) ? counts[i] : 0;
    s[tid] = v;
    __syncthreads();
    for (int off = 1; off < SCAN_B; off <<= 1) {
        int t = (tid >= off) ? s[tid - off] : 0;
        __syncthreads();
        s[tid] += t;
        __syncthreads();
    }
    if (i < N_NODES) rowp[i] = s[tid] - v;
    if (tid == SCAN_B - 1) partials[blockIdx.x] = s[SCAN_B - 1];
}

__global__ __launch_bounds__(SCAN_B) void k_scan_add(int* __restrict__ rowp,
                                                     int* __restrict__ cursor,
                                                     const int* __restrict__ partials,
                                                     const int* __restrict__ counts,
                                                     float* __restrict__ dinv) {
    __shared__ int s[SCAN_B];
    const int tid = threadIdx.x;
    const int b = blockIdx.x;
    int v = (tid < b) ? partials[tid] : 0;
    s[tid] = v;
    __syncthreads();
    for (int off = SCAN_B / 2; off > 0; off >>= 1) {
        if (tid < off) s[tid] += s[tid + off];
        __syncthreads();
    }
    const int offset = s[0];
    const int i = b * SCAN_B + tid;
    if (i < N_NODES) {
        int r = rowp[i] + offset;
        rowp[i] = r;
        cursor[i] = r;
        dinv[i] = rsqrtf(1.0f + (float)counts[i]);
    }
    if (b == 0 && tid == 0) rowp[N_NODES] = N_EDGES;
}

// scatter + per-edge normalized weight (removes dinv from gather chain)
__global__ void k_scatter(const int* __restrict__ src, const int* __restrict__ dst,
                          int* __restrict__ cursor, int* __restrict__ ssrc,
                          const float* __restrict__ dinv, float* __restrict__ wnorm) {
    int e = blockIdx.x * blockDim.x + threadIdx.x;
    if (e < N_EDGES) {
        int d = dst[e], s = src[e];
        int p = atomicAdd(&cursor[d], 1);
        ssrc[p] = s;
        wnorm[p] = dinv[s] * dinv[d];
    }
}

// ---------------- fused layer: gather (+BN-load) -> LDS A-tile -> MFMA --------
// Block: 16 nodes. Phase 1: each wave aggregates 4 nodes into LDS (bf16).
// Phase 2: 4 waves x 4 col-tiles MFMA vs packed W; bias; bf16 C; stats partials.
template <int KIN, bool BN>
__global__ __launch_bounds__(256) void k_fused(const unsigned short* __restrict__ Xin,
                                               const int* __restrict__ rowp,
                                               const int* __restrict__ ssrc,
                                               const float* __restrict__ wnorm,
                                               const float* __restrict__ dinv,
                                               const float* __restrict__ scale,
                                               const float* __restrict__ shift,
                                               const short* __restrict__ Bp,
                                               const float* __restrict__ bias,
                                               unsigned short* __restrict__ C,
                                               float* __restrict__ bnp) {
    constexpr int nkt = KIN / 32;
    constexpr int LROW = KIN + 8;
    __shared__ __align__(16) unsigned short At[16 * LROW];
    const int wave = threadIdx.x >> 6;
    const int lane = threadIdx.x & 63;

    // ---- phase 1: gather ----
    if constexpr (KIN == 128) {
        const unsigned* Xu = (const unsigned*)Xin;   // 2 feats/lane
#pragma unroll
        for (int nn = 0; nn < 4; nn++) {
            const int r = wave * 4 + nn;
            const int node = blockIdx.x * 16 + r;
            const float dd = dinv[node];
            const float sw = dd * dd;
            unsigned v = Xu[node * 64 + lane];
            float a0 = sw * bf2f((unsigned short)(v & 0xffff));
            float a1 = sw * bf2f((unsigned short)(v >> 16));
            const int e0 = rowp[node], e1 = rowp[node + 1];
            int j = e0;
            for (; j + 3 < e1; j += 4) {
                const int i0 = ssrc[j], i1 = ssrc[j + 1], i2 = ssrc[j + 2], i3 = ssrc[j + 3];
                const float w0 = wnorm[j], w1 = wnorm[j + 1];
                const float w2 = wnorm[j + 2], w3 = wnorm[j + 3];
                const unsigned u0 = Xu[i0 * 64 + lane], u1 = Xu[i1 * 64 + lane];
                const unsigned u2 = Xu[i2 * 64 + lane], u3 = Xu[i3 * 64 + lane];
                a0 += w0 * bf2f((unsigned short)(u0 & 0xffff)) + w1 * bf2f((unsigned short)(u1 & 0xffff))
                    + w2 * bf2f((unsigned short)(u2 & 0xffff)) + w3 * bf2f((unsigned short)(u3 & 0xffff));
                a1 += w0 * bf2f((unsigned short)(u0 >> 16)) + w1 * bf2f((unsigned short)(u1 >> 16))
                    + w2 * bf2f((unsigned short)(u2 >> 16)) + w3 * bf2f((unsigned short)(u3 >> 16));
            }
            for (; j < e1; j++) {
                const int s = ssrc[j];
                const float w = wnorm[j];
                const unsigned u = Xu[s * 64 + lane];
                a0 += w * bf2f((unsigned short)(u & 0xffff));
                a1 += w * bf2f((unsigned short)(u >> 16));
            }
            *(unsigned*)&At[r * LROW + lane * 2] =
                (unsigned)f2bf(a0) | ((unsigned)f2bf(a1) << 16);
        }
    } else {
        const ushort4* Xu = (const ushort4*)Xin;     // 4 feats/lane
        const float4 sc = BN ? *(const float4*)(scale + lane * 4) : float4{0, 0, 0, 0};
        const float4 sh = BN ? *(const float4*)(shift + lane * 4) : float4{0, 0, 0, 0};
#pragma unroll
        for (int nn = 0; nn < 4; nn++) {
            const int r = wave * 4 + nn;
            const int node = blockIdx.x * 16 + r;
            const float dd = dinv[node];
            const float sw = dd * dd;
            ushort4 v = Xu[node * 64 + lane];
            float a0 = sw * fmaxf(sc.x * bf2f(v.x) + sh.x, 0.f);
            float a1 = sw * fmaxf(sc.y * bf2f(v.y) + sh.y, 0.f);
            float a2 = sw * fmaxf(sc.z * bf2f(v.z) + sh.z, 0.f);
            float a3 = sw * fmaxf(sc.w * bf2f(v.w) + sh.w, 0.f);
            const int e0 = rowp[node], e1 = rowp[node + 1];
            int j = e0;
            for (; j + 3 < e1; j += 4) {
                const int i0 = ssrc[j], i1 = ssrc[j + 1], i2 = ssrc[j + 2], i3 = ssrc[j + 3];
                const float w0 = wnorm[j], w1 = wnorm[j + 1];
                const float w2 = wnorm[j + 2], w3 = wnorm[j + 3];
                ushort4 u0 = Xu[i0 * 64 + lane];
                ushort4 u1 = Xu[i1 * 64 + lane];
                ushort4 u2 = Xu[i2 * 64 + lane];
                ushort4 u3 = Xu[i3 * 64 + lane];
                a0 += w0 * fmaxf(sc.x * bf2f(u0.x) + sh.x, 0.f) + w1 * fmaxf(sc.x * bf2f(u1.x) + sh.x, 0.f)
                    + w2 * fmaxf(sc.x * bf2f(u2.x) + sh.x, 0.f) + w3 * fmaxf(sc.x * bf2f(u3.x) + sh.x, 0.f);
                a1 += w0 * fmaxf(sc.y * bf2f(u0.y) + sh.y, 0.f) + w1 * fmaxf(sc.y * bf2f(u1.y) + sh.y, 0.f)
                    + w2 * fmaxf(sc.y * bf2f(u2.y) + sh.y, 0.f) + w3 * fmaxf(sc.y * bf2f(u3.y) + sh.y, 0.f);
                a2 += w0 * fmaxf(sc.z * bf2f(u0.z) + sh.z, 0.f) + w1 * fmaxf(sc.z * bf2f(u1.z) + sh.z, 0.f)
                    + w2 * fmaxf(sc.z * bf2f(u2.z) + sh.z, 0.f) + w3 * fmaxf(sc.z * bf2f(u3.z) + sh.z, 0.f);
                a3 += w0 * fmaxf(sc.w * bf2f(u0.w) + sh.w, 0.f) + w1 * fmaxf(sc.w * bf2f(u1.w) + sh.w, 0.f)
                    + w2 * fmaxf(sc.w * bf2f(u2.w) + sh.w, 0.f) + w3 * fmaxf(sc.w * bf2f(u3.w) + sh.w, 0.f);
            }
            for (; j < e1; j++) {
                const int s = ssrc[j];
                const float w = wnorm[j];
                ushort4 u = Xu[s * 64 + lane];
                a0 += w * fmaxf(sc.x * bf2f(u.x) + sh.x, 0.f);
                a1 += w * fmaxf(sc.y * bf2f(u.y) + sh.y, 0.f);
                a2 += w * fmaxf(sc.z * bf2f(u.z) + sh.z, 0.f);
                a3 += w * fmaxf(sc.w * bf2f(u.w) + sh.w, 0.f);
            }
            ushort4 o;
            o.x = f2bf(a0); o.y = f2bf(a1); o.z = f2bf(a2); o.w = f2bf(a3);
            *(ushort4*)&At[r * LROW + lane * 4] = o;
        }
    }
    __syncthreads();

    // ---- phase 2: MFMA ----
    const int rowb = blockIdx.x * 16;
    const int ntile0 = wave * 4;
    const unsigned short* aL = &At[(lane & 15) * LROW + (lane >> 4) * 8];
    f32x4 acc[4] = {};
#pragma unroll
    for (int kt = 0; kt < nkt; kt++) {
        bf16x8 af = *(const bf16x8*)(aL + kt * 32);
#pragma unroll
        for (int nt = 0; nt < 4; nt++) {
            bf16x8 bfr = *(const bf16x8*)(Bp + (((size_t)(ntile0 + nt) * nkt + kt) * 64 + lane) * 8);
            acc[nt] = __builtin_amdgcn_mfma_f32_16x16x32_bf16(af, bfr, acc[nt], 0, 0, 0);
        }
    }
    const int rg = lane >> 4, cc = lane & 15;    // C/D: col=lane&15, row=rg*4+i
    float s[4], q[4];
#pragma unroll
    for (int nt = 0; nt < 4; nt++) {
        const int col = (ntile0 + nt) * 16 + cc;
        const float b = bias[col];
        f32x4 a = acc[nt];
        a[0] += b; a[1] += b; a[2] += b; a[3] += b;
        const size_t base = (size_t)(rowb + rg * 4) * HIDDEN + col;
#pragma unroll
        for (int i = 0; i < 4; i++) C[base + (size_t)i * HIDDEN] = f2bf(a[i]);
        s[nt] = a[0] + a[1] + a[2] + a[3];
        q[nt] = a[0]*a[0] + a[1]*a[1] + a[2]*a[2] + a[3]*a[3];
    }
#pragma unroll
    for (int nt = 0; nt < 4; nt++) {
        s[nt] += __shfl_xor(s[nt], 16); s[nt] += __shfl_xor(s[nt], 32);
        q[nt] += __shfl_xor(q[nt], 16); q[nt] += __shfl_xor(q[nt], 32);
    }
    if (lane < 16) {
        float* dst = bnp + (size_t)blockIdx.x * 512 + ntile0 * 16 + lane;
#pragma unroll
        for (int nt = 0; nt < 4; nt++) {
            dst[nt * 16]       = s[nt];
            dst[nt * 16 + 256] = q[nt];
        }
    }
}

// ---------------- BN partial reduce: bnp[GNB][512] -> bnp2[32][512] ----------
__global__ __launch_bounds__(512) void k_bnred(const float* __restrict__ bnp,
                                               float* __restrict__ bnp2) {
    const int t = threadIdx.x;                 // 0..511
    const int b = blockIdx.x;                  // 32
    const int per = (GNB + 31) / 32;           // 98
    int r0 = b * per, r1 = r0 + per; if (r1 > GNB) r1 = GNB;
    float s = 0.f;
    for (int r = r0; r < r1; r++) s += bnp[(size_t)r * 512 + t];
    bnp2[(size_t)b * 512 + t] = s;
}

// ---------------- BN prep: bnp2 -> scale/shift ----------------
__global__ __launch_bounds__(256) void k_bnprep(const float* __restrict__ bnp2,
                                                const float* __restrict__ g,
                                                const float* __restrict__ be,
                                                float* __restrict__ scale,
                                                float* __restrict__ shift) {
    const int f = threadIdx.x;
    float s = 0.f, q = 0.f;
#pragma unroll
    for (int b = 0; b < 32; b++) {
        s += bnp2[(size_t)b * 512 + f];
        q += bnp2[(size_t)b * 512 + 256 + f];
    }
    const float inv_n = 1.0f / (float)N_NODES;
    float mean = s * inv_n;
    float var = q * inv_n - mean * mean;
    var = fmaxf(var, 0.f);
    float sc = g[f] * rsqrtf(var + BN_EPS);
    scale[f] = sc;
    shift[f] = be[f] - mean * sc;
}

// ---------------- GEMM3: XW3 = relu(bn(H2)) @ W3, fp32 out, 1 wave MT=3 ------
template <int K_>
__global__ __launch_bounds__(64) void k_gemm3(const unsigned short* __restrict__ A,
                                              const short* __restrict__ Bp,
                                              const float* __restrict__ scale,
                                              const float* __restrict__ shift,
                                              float* __restrict__ C) {
    constexpr int nkt = K_ / 32;
    constexpr int MT = 3;
    const int lane = threadIdx.x & 63;
    const int rowb = blockIdx.x * 16;
    const int koff = (lane >> 4) * 8;
    const unsigned short* aptr = A + (size_t)(rowb + (lane & 15)) * K_ + koff;
    f32x4 acc[MT] = {};
#pragma unroll
    for (int kt = 0; kt < nkt; kt++) {
        ushort8 a8 = *(const ushort8*)(aptr + kt * 32);
        const int kb = kt * 32 + koff;
        float4 s0 = *(const float4*)(scale + kb);
        float4 s1 = *(const float4*)(scale + kb + 4);
        float4 t0 = *(const float4*)(shift + kb);
        float4 t1 = *(const float4*)(shift + kb + 4);
        bf16x8 af;
        af[0] = (short)f2bf(fmaxf(s0.x * bf2f(a8[0]) + t0.x, 0.f));
        af[1] = (short)f2bf(fmaxf(s0.y * bf2f(a8[1]) + t0.y, 0.f));
        af[2] = (short)f2bf(fmaxf(s0.z * bf2f(a8[2]) + t0.z, 0.f));
        af[3] = (short)f2bf(fmaxf(s0.w * bf2f(a8[3]) + t0.w, 0.f));
        af[4] = (short)f2bf(fmaxf(s1.x * bf2f(a8[4]) + t1.x, 0.f));
        af[5] = (short)f2bf(fmaxf(s1.y * bf2f(a8[5]) + t1.y, 0.f));
        af[6] = (short)f2bf(fmaxf(s1.z * bf2f(a8[6]) + t1.z, 0.f));
        af[7] = (short)f2bf(fmaxf(s1.w * bf2f(a8[7]) + t1.w, 0.f));
#pragma unroll
        for (int nt = 0; nt < MT; nt++) {
            bf16x8 bfr = *(const bf16x8*)(Bp + (((size_t)nt * nkt + kt) * 64 + lane) * 8);
            acc[nt] = __builtin_amdgcn_mfma_f32_16x16x32_bf16(af, bfr, acc[nt], 0, 0, 0);
        }
    }
    const int rg = lane >> 4, cc = lane & 15;
#pragma unroll
    for (int nt = 0; nt < MT; nt++) {
        const int col = nt * 16 + cc;
        if (col < NCLS) {
            const size_t base = (size_t)(rowb + rg * 4) * NCLS + col;
#pragma unroll
            for (int i = 0; i < 4; i++) C[base + (size_t)i * NCLS] = acc[nt][i];
        }
    }
}

// ---------------- output: gather F=40 + bias + log_softmax, one wave/node ----
__global__ __launch_bounds__(256) void k_out(const float* __restrict__ XW,
                                             const int* __restrict__ rowp,
                                             const int* __restrict__ ssrc,
                                             const float* __restrict__ wnorm,
                                             const float* __restrict__ dinv,
                                             const float* __restrict__ bias,
                                             float* __restrict__ out) {
    const int wave = threadIdx.x >> 6;
    const int lane = threadIdx.x & 63;
    const int node = blockIdx.x * 4 + wave;
    const float dd = dinv[node];
    const bool act = lane < NCLS;
    float acc = 0.f;
    if (act) acc = dd * dd * XW[node * NCLS + lane];
    const int e0 = rowp[node], e1 = rowp[node + 1];
    int j = e0;
    for (; j + 1 < e1; j += 2) {
        const int i0 = ssrc[j], i1 = ssrc[j + 1];
        const float w0 = wnorm[j], w1 = wnorm[j + 1];
        float v0 = 0.f, v1 = 0.f;
        if (act) { v0 = XW[i0 * NCLS + lane]; v1 = XW[i1 * NCLS + lane]; }
        acc += w0 * v0 + w1 * v1;
    }
    for (; j < e1; j++) {
        const int s = ssrc[j];
        const float w = wnorm[j];
        if (act) acc += w * XW[s * NCLS + lane];
    }
    if (act) acc += bias[lane];
    float m = act ? acc : -1e30f;
#pragma unroll
    for (int off = 32; off > 0; off >>= 1) m = fmaxf(m, __shfl_xor(m, off));
    float e = act ? expf(acc - m) : 0.f;
#pragma unroll
    for (int off = 32; off > 0; off >>= 1) e += __shfl_xor(e, off);
    const float lse = m + logf(e);
    if (act) out[node * NCLS + lane] = acc - lse;
}

extern "C" void kernel_launch(void* const* d_in, const int* in_sizes, int n_in,
                              void* d_out, int out_size, void* d_ws, size_t ws_size,
                              hipStream_t stream) {
    const float* x   = (const float*)d_in[0];
    const int*   ei  = (const int*)d_in[1];
    const float* W1  = (const float*)d_in[2];
    const float* b1  = (const float*)d_in[3];
    const float* g1  = (const float*)d_in[4];
    const float* be1 = (const float*)d_in[5];
    const float* W2  = (const float*)d_in[6];
    const float* b2  = (const float*)d_in[7];
    const float* g2  = (const float*)d_in[8];
    const float* be2 = (const float*)d_in[9];
    const float* W3  = (const float*)d_in[10];
    const float* b3  = (const float*)d_in[11];
    float* out = (float*)d_out;

    const int* e_src = ei;
    const int* e_dst = ei + N_EDGES;

    // ---- workspace layout ----
    char* w = (char*)d_ws;
    unsigned short* Xb  = (unsigned short*)w;  w += (size_t)N_NODES * IN_FEAT * 2;  // 12.8 MB
    unsigned short* H1b = (unsigned short*)w;  w += (size_t)N_NODES * HIDDEN * 2;   // 25.6 MB
    unsigned short* H2b = (unsigned short*)w;  w += (size_t)N_NODES * HIDDEN * 2;   // 25.6 MB
    float* XW3    = (float*)w;                 w += (size_t)N_NODES * NCLS * 4;     // 8 MB
    float* bnp    = (float*)w;                 w += (size_t)GNB * 512 * 4;          // 6.4 MB
    float* bnp2   = (float*)w;                 w += (size_t)32 * 512 * 4;           // 64 KB
    float* dinv   = (float*)w;                 w += (size_t)N_NODES * 4;
    float* wnorm  = (float*)w;                 w += (size_t)N_EDGES * 4;            // 1.28 MB
    int*   counts = (int*)w;                   w += (size_t)N_NODES * 4;
    int*   rowp   = (int*)w;                   w += (size_t)(N_NODES + 4) * 4;
    int*   cursor = (int*)w;                   w += (size_t)N_NODES * 4;
    int*   ssrc   = (int*)w;                   w += (size_t)N_EDGES * 4;
    int*   partials=(int*)w;                   w += 256 * 4;
    float* scale1 = (float*)w;                 w += 256 * 4;
    float* shift1 = (float*)w;                 w += 256 * 4;
    float* scale2 = (float*)w;                 w += 256 * 4;
    float* shift2 = (float*)w;                 w += 256 * 4;
    unsigned short* W1p = (unsigned short*)w;  w += (size_t)16 * 4 * 64 * 8 * 2;    // 64 KB
    unsigned short* W2p = (unsigned short*)w;  w += (size_t)16 * 8 * 64 * 8 * 2;    // 128 KB
    unsigned short* W3p = (unsigned short*)w;  w += (size_t)3 * 8 * 64 * 8 * 2;     // 24 KB

    const int EB = (N_EDGES + 255) / 256;

    // ---- CSR build + prep (hist fused with cast/pack) ----
    hipMemsetAsync(counts, 0, (size_t)N_NODES * 4, stream);
    k_prep<<<PREP_HIST_NB + PREP_CVT_NB + PREP_PACK_NB, 256, 0, stream>>>(
        e_dst, counts, x, (ushort8*)Xb, W1, W2, W3, W1p, W2p, W3p);
    k_scan_local<<<SCAN_NB, SCAN_B, 0, stream>>>(counts, rowp, partials);
    k_scan_add<<<SCAN_NB, SCAN_B, 0, stream>>>(rowp, cursor, partials, counts, dinv);
    k_scatter<<<EB, 256, 0, stream>>>(e_src, e_dst, cursor, ssrc, dinv, wnorm);

    // ---- layer 1: fused (gather X -> MFMA W1 + b1 -> H1b, stats) ----
    k_fused<IN_FEAT, false><<<GNB, 256, 0, stream>>>(
        Xb, rowp, ssrc, wnorm, dinv, nullptr, nullptr, (const short*)W1p, b1, H1b, bnp);
    k_bnred<<<32, 512, 0, stream>>>(bnp, bnp2);
    k_bnprep<<<1, 256, 0, stream>>>(bnp2, g1, be1, scale1, shift1);

    // ---- layer 2: fused (gather relu(bn(H1)) -> MFMA W2 + b2 -> H2b, stats) --
    k_fused<HIDDEN, true><<<GNB, 256, 0, stream>>>(
        H1b, rowp, ssrc, wnorm, dinv, scale1, shift1, (const short*)W2p, b2, H2b, bnp);
    k_bnred<<<32, 512, 0, stream>>>(bnp, bnp2);
    k_bnprep<<<1, 256, 0, stream>>>(bnp2, g2, be2, scale2, shift2);

    // ---- output layer ----
    k_gemm3<HIDDEN><<<GNB, 64, 0, stream>>>(H2b, (const short*)W3p, scale2, shift2, XW3);
    k_out<<<N_NODES / 4, 256, 0, stream>>>(XW3, rowp, ssrc, wnorm, dinv, b3, out);
}

// Round 11
// 316.495 us; speedup vs baseline: 1.0046x; 1.0046x over previous
//
#include <hip/hip_runtime.h>

#define N_NODES 50000
#define N_EDGES 320000
#define IN_FEAT 128
#define HIDDEN  256
#define NCLS    40
#define BN_EPS  1e-5f

#define SCAN_B  256
#define SCAN_NB ((N_NODES + SCAN_B - 1) / SCAN_B)   // 196
#define GNB     (N_NODES / 16)                      // 3125 blocks, 16 nodes each

// prep kernel partition
#define PREP_HIST_NB  (N_EDGES / 256)               // 1250
#define PREP_CVT_NB   (N_NODES * IN_FEAT / 8 / 256) // 3125
#define PREP_PACK_NB  54                            // 216 wave-units / 4

typedef __attribute__((ext_vector_type(8))) short bf16x8;
typedef __attribute__((ext_vector_type(4))) float f32x4;
typedef __attribute__((ext_vector_type(8))) unsigned short ushort8;

__device__ __forceinline__ unsigned short f2bf(float f) {
    union { float f; unsigned u; } a; a.f = f;
    unsigned r = a.u + 0x7fff + ((a.u >> 16) & 1);   // RNE
    return (unsigned short)(r >> 16);
}
__device__ __forceinline__ float bf2f(unsigned short u) {
    union { unsigned u; float f; } a; a.u = ((unsigned)u) << 16;
    return a.f;
}

__device__ __forceinline__ void packB_unit(const float* __restrict__ W,
                                           unsigned short* __restrict__ Bp,
                                           int nt, int kt, int nkt, int M, int lane) {
    const int n = nt * 16 + (lane & 15);
    const int kb = kt * 32 + (lane >> 4) * 8;
    unsigned short* dst = Bp + (((size_t)nt * nkt + kt) * 64 + lane) * 8;
#pragma unroll
    for (int j = 0; j < 8; j++)
        dst[j] = (n < M) ? f2bf(W[(size_t)(kb + j) * M + n]) : (unsigned short)0;
}

// ---------------- merged prep: hist + x cast + W packs ----------------
__global__ __launch_bounds__(256) void k_prep(const int* __restrict__ e_dst,
                                              int* __restrict__ counts,
                                              const float* __restrict__ x,
                                              ushort8* __restrict__ Xb,
                                              const float* __restrict__ W1,
                                              const float* __restrict__ W2,
                                              const float* __restrict__ W3,
                                              unsigned short* __restrict__ W1p,
                                              unsigned short* __restrict__ W2p,
                                              unsigned short* __restrict__ W3p) {
    const int b = blockIdx.x;
    const int tid = threadIdx.x;
    if (b < PREP_HIST_NB) {
        const int e = b * 256 + tid;                  // 1250*256 == N_EDGES
        atomicAdd(&counts[e_dst[e]], 1);
    } else if (b < PREP_HIST_NB + PREP_CVT_NB) {
        const int i = (b - PREP_HIST_NB) * 256 + tid; // exact cover
        float4 a = *(const float4*)(x + (size_t)i * 8);
        float4 c = *(const float4*)(x + (size_t)i * 8 + 4);
        ushort8 o = {f2bf(a.x), f2bf(a.y), f2bf(a.z), f2bf(a.w),
                     f2bf(c.x), f2bf(c.y), f2bf(c.z), f2bf(c.w)};
        Xb[i] = o;
    } else {
        const int wave = tid >> 6, lane = tid & 63;
        const int u = (b - PREP_HIST_NB - PREP_CVT_NB) * 4 + wave;  // 0..215
        if (u < 64) {
            packB_unit(W1, W1p, u >> 2, u & 3, 4, HIDDEN, lane);
        } else if (u < 192) {
            const int v = u - 64;
            packB_unit(W2, W2p, v >> 3, v & 7, 8, HIDDEN, lane);
        } else {
            const int v = u - 192;
            packB_unit(W3, W3p, v >> 3, v & 7, 8, NCLS, lane);
        }
    }
}

// ---------------- CSR scan ----------------
__global__ __launch_bounds__(SCAN_B) void k_scan_local(const int* __restrict__ counts,
                                                       int* __restrict__ rowp,
                                                       int* __restrict__ partials) {
    __shared__ int s[SCAN_B];
    const int tid = threadIdx.x;
    const int i = blockIdx.x * SCAN_B + tid;
    int v = (i < N_NODES) ? counts[i] : 0;
    s[tid] = v;
    __syncthreads();
    for (int off = 1; off < SCAN_B; off <<= 1) {
        int t = (tid >= off) ? s[tid - off] : 0;
        __syncthreads();
        s[tid] += t;
        __syncthreads();
    }
    if (i < N_NODES) rowp[i] = s[tid] - v;
    if (tid == SCAN_B - 1) partials[blockIdx.x] = s[SCAN_B - 1];
}

__global__ __launch_bounds__(SCAN_B) void k_scan_add(int* __restrict__ rowp,
                                                     int* __restrict__ cursor,
                                                     const int* __restrict__ partials,
                                                     const int* __restrict__ counts,
                                                     float* __restrict__ dinv) {
    __shared__ int s[SCAN_B];
    const int tid = threadIdx.x;
    const int b = blockIdx.x;
    int v = (tid < b) ? partials[tid] : 0;
    s[tid] = v;
    __syncthreads();
    for (int off = SCAN_B / 2; off > 0; off >>= 1) {
        if (tid < off) s[tid] += s[tid + off];
        __syncthreads();
    }
    const int offset = s[0];
    const int i = b * SCAN_B + tid;
    if (i < N_NODES) {
        int r = rowp[i] + offset;
        rowp[i] = r;
        cursor[i] = r;
        dinv[i] = rsqrtf(1.0f + (float)counts[i]);
    }
    if (b == 0 && tid == 0) rowp[N_NODES] = N_EDGES;
}

// scatter + per-edge normalized weight
__global__ void k_scatter(const int* __restrict__ src, const int* __restrict__ dst,
                          int* __restrict__ cursor, int* __restrict__ ssrc,
                          const float* __restrict__ dinv, float* __restrict__ wnorm) {
    int e = blockIdx.x * blockDim.x + threadIdx.x;
    if (e < N_EDGES) {
        int d = dst[e], s = src[e];
        int p = atomicAdd(&cursor[d], 1);
        ssrc[p] = s;
        wnorm[p] = dinv[s] * dinv[d];
    }
}

// ---------------- fused layer: interleaved gather -> LDS A-tile -> MFMA -------
// Block: 16 nodes (4/wave). Gather interleaves all 4 nodes: 16 row loads in
// flight per iteration; exhausted nodes clamp to a repeated (cached) row, w=0.
template <int KIN, bool BN>
__global__ __launch_bounds__(256) void k_fused(const unsigned short* __restrict__ Xin,
                                               const int* __restrict__ rowp,
                                               const int* __restrict__ ssrc,
                                               const float* __restrict__ wnorm,
                                               const float* __restrict__ dinv,
                                               const float* __restrict__ scale,
                                               const float* __restrict__ shift,
                                               const short* __restrict__ Bp,
                                               const float* __restrict__ bias,
                                               unsigned short* __restrict__ C,
                                               float* __restrict__ bnp) {
    constexpr int nkt = KIN / 32;
    constexpr int LROW = KIN + 8;
    __shared__ __align__(16) unsigned short At[16 * LROW];
    const int wave = threadIdx.x >> 6;
    const int lane = threadIdx.x & 63;
    const int node0 = blockIdx.x * 16 + wave * 4;

    int p[4], q[4];
#pragma unroll
    for (int i = 0; i < 4; i++) {
        p[i] = rowp[node0 + i];
        q[i] = rowp[node0 + i + 1];
    }

    if constexpr (KIN == 128) {
        const unsigned* Xu = (const unsigned*)Xin;   // 2 feats/lane
        float a0[4], a1[4];
#pragma unroll
        for (int i = 0; i < 4; i++) {
            const float dd = dinv[node0 + i];
            const float sw = dd * dd;
            unsigned v = Xu[(size_t)(node0 + i) * 64 + lane];
            a0[i] = sw * bf2f((unsigned short)(v & 0xffff));
            a1[i] = sw * bf2f((unsigned short)(v >> 16));
        }
        while ((p[0] < q[0]) | (p[1] < q[1]) | (p[2] < q[2]) | (p[3] < q[3])) {
            int idx[16]; float wt[16];
#pragma unroll
            for (int i = 0; i < 4; i++) {
#pragma unroll
                for (int k = 0; k < 4; k++) {
                    int jj = p[i] + k;
                    int jc = jj < q[i] ? jj : (q[i] > 0 ? q[i] - 1 : 0);
                    idx[i * 4 + k] = ssrc[jc];
                    wt[i * 4 + k] = (jj < q[i]) ? wnorm[jc] : 0.f;
                }
            }
            unsigned r[16];
#pragma unroll
            for (int s = 0; s < 16; s++) r[s] = Xu[(size_t)idx[s] * 64 + lane];
#pragma unroll
            for (int i = 0; i < 4; i++) {
#pragma unroll
                for (int k = 0; k < 4; k++) {
                    const unsigned u = r[i * 4 + k];
                    const float w = wt[i * 4 + k];
                    a0[i] += w * bf2f((unsigned short)(u & 0xffff));
                    a1[i] += w * bf2f((unsigned short)(u >> 16));
                }
            }
#pragma unroll
            for (int i = 0; i < 4; i++) p[i] = (p[i] + 4 < q[i]) ? p[i] + 4 : q[i];
        }
#pragma unroll
        for (int i = 0; i < 4; i++)
            *(unsigned*)&At[(wave * 4 + i) * LROW + lane * 2] =
                (unsigned)f2bf(a0[i]) | ((unsigned)f2bf(a1[i]) << 16);
    } else {
        const ushort4* Xu = (const ushort4*)Xin;     // 4 feats/lane
        const float4 sc = *(const float4*)(scale + lane * 4);
        const float4 sh = *(const float4*)(shift + lane * 4);
        float a0[4], a1[4], a2[4], a3[4];
#pragma unroll
        for (int i = 0; i < 4; i++) {
            const float dd = dinv[node0 + i];
            const float sw = dd * dd;
            ushort4 v = Xu[(size_t)(node0 + i) * 64 + lane];
            a0[i] = sw * fmaxf(sc.x * bf2f(v.x) + sh.x, 0.f);
            a1[i] = sw * fmaxf(sc.y * bf2f(v.y) + sh.y, 0.f);
            a2[i] = sw * fmaxf(sc.z * bf2f(v.z) + sh.z, 0.f);
            a3[i] = sw * fmaxf(sc.w * bf2f(v.w) + sh.w, 0.f);
        }
        while ((p[0] < q[0]) | (p[1] < q[1]) | (p[2] < q[2]) | (p[3] < q[3])) {
            int idx[16]; float wt[16];
#pragma unroll
            for (int i = 0; i < 4; i++) {
#pragma unroll
                for (int k = 0; k < 4; k++) {
                    int jj = p[i] + k;
                    int jc = jj < q[i] ? jj : (q[i] > 0 ? q[i] - 1 : 0);
                    idx[i * 4 + k] = ssrc[jc];
                    wt[i * 4 + k] = (jj < q[i]) ? wnorm[jc] : 0.f;
                }
            }
            ushort4 r[16];
#pragma unroll
            for (int s = 0; s < 16; s++) r[s] = Xu[(size_t)idx[s] * 64 + lane];
#pragma unroll
            for (int i = 0; i < 4; i++) {
#pragma unroll
                for (int k = 0; k < 4; k++) {
                    const ushort4 u = r[i * 4 + k];
                    const float w = wt[i * 4 + k];
                    a0[i] += w * fmaxf(sc.x * bf2f(u.x) + sh.x, 0.f);
                    a1[i] += w * fmaxf(sc.y * bf2f(u.y) + sh.y, 0.f);
                    a2[i] += w * fmaxf(sc.z * bf2f(u.z) + sh.z, 0.f);
                    a3[i] += w * fmaxf(sc.w * bf2f(u.w) + sh.w, 0.f);
                }
            }
#pragma unroll
            for (int i = 0; i < 4; i++) p[i] = (p[i] + 4 < q[i]) ? p[i] + 4 : q[i];
        }
#pragma unroll
        for (int i = 0; i < 4; i++) {
            ushort4 o;
            o.x = f2bf(a0[i]); o.y = f2bf(a1[i]);
            o.z = f2bf(a2[i]); o.w = f2bf(a3[i]);
            *(ushort4*)&At[(wave * 4 + i) * LROW + lane * 4] = o;
        }
    }
    __syncthreads();

    // ---- phase 2: MFMA ----
    const int rowb = blockIdx.x * 16;
    const int ntile0 = wave * 4;
    const unsigned short* aL = &At[(lane & 15) * LROW + (lane >> 4) * 8];
    f32x4 acc[4] = {};
#pragma unroll
    for (int kt = 0; kt < nkt; kt++) {
        bf16x8 af = *(const bf16x8*)(aL + kt * 32);
#pragma unroll
        for (int nt = 0; nt < 4; nt++) {
            bf16x8 bfr = *(const bf16x8*)(Bp + (((size_t)(ntile0 + nt) * nkt + kt) * 64 + lane) * 8);
            acc[nt] = __builtin_amdgcn_mfma_f32_16x16x32_bf16(af, bfr, acc[nt], 0, 0, 0);
        }
    }
    const int rg = lane >> 4, cc = lane & 15;    // C/D: col=lane&15, row=rg*4+i
    float s[4], q2[4];
#pragma unroll
    for (int nt = 0; nt < 4; nt++) {
        const int col = (ntile0 + nt) * 16 + cc;
        const float b = bias[col];
        f32x4 a = acc[nt];
        a[0] += b; a[1] += b; a[2] += b; a[3] += b;
        const size_t base = (size_t)(rowb + rg * 4) * HIDDEN + col;
#pragma unroll
        for (int i = 0; i < 4; i++) C[base + (size_t)i * HIDDEN] = f2bf(a[i]);
        s[nt] = a[0] + a[1] + a[2] + a[3];
        q2[nt] = a[0]*a[0] + a[1]*a[1] + a[2]*a[2] + a[3]*a[3];
    }
#pragma unroll
    for (int nt = 0; nt < 4; nt++) {
        s[nt] += __shfl_xor(s[nt], 16); s[nt] += __shfl_xor(s[nt], 32);
        q2[nt] += __shfl_xor(q2[nt], 16); q2[nt] += __shfl_xor(q2[nt], 32);
    }
    if (lane < 16) {
        float* dst = bnp + (size_t)blockIdx.x * 512 + ntile0 * 16 + lane;
#pragma unroll
        for (int nt = 0; nt < 4; nt++) {
            dst[nt * 16]       = s[nt];
            dst[nt * 16 + 256] = q2[nt];
        }
    }
}

// ---------------- BN partial reduce: bnp[GNB][512] -> bnp2[32][512] ----------
__global__ __launch_bounds__(512) void k_bnred(const float* __restrict__ bnp,
                                               float* __restrict__ bnp2) {
    const int t = threadIdx.x;
    const int b = blockIdx.x;                  // 32
    const int per = (GNB + 31) / 32;           // 98
    int r0 = b * per, r1 = r0 + per; if (r1 > GNB) r1 = GNB;
    float s = 0.f;
    for (int r = r0; r < r1; r++) s += bnp[(size_t)r * 512 + t];
    bnp2[(size_t)b * 512 + t] = s;
}

// ---------------- BN prep: bnp2 -> scale/shift ----------------
__global__ __launch_bounds__(256) void k_bnprep(const float* __restrict__ bnp2,
                                                const float* __restrict__ g,
                                                const float* __restrict__ be,
                                                float* __restrict__ scale,
                                                float* __restrict__ shift) {
    const int f = threadIdx.x;
    float s = 0.f, q = 0.f;
#pragma unroll
    for (int b = 0; b < 32; b++) {
        s += bnp2[(size_t)b * 512 + f];
        q += bnp2[(size_t)b * 512 + 256 + f];
    }
    const float inv_n = 1.0f / (float)N_NODES;
    float mean = s * inv_n;
    float var = q * inv_n - mean * mean;
    var = fmaxf(var, 0.f);
    float sc = g[f] * rsqrtf(var + BN_EPS);
    scale[f] = sc;
    shift[f] = be[f] - mean * sc;
}

// ---------------- GEMM3: XW3 = relu(bn(H2)) @ W3, fp32 out, 1 wave MT=3 ------
template <int K_>
__global__ __launch_bounds__(64) void k_gemm3(const unsigned short* __restrict__ A,
                                              const short* __restrict__ Bp,
                                              const float* __restrict__ scale,
                                              const float* __restrict__ shift,
                                              float* __restrict__ C) {
    constexpr int nkt = K_ / 32;
    constexpr int MT = 3;
    const int lane = threadIdx.x & 63;
    const int rowb = blockIdx.x * 16;
    const int koff = (lane >> 4) * 8;
    const unsigned short* aptr = A + (size_t)(rowb + (lane & 15)) * K_ + koff;
    f32x4 acc[MT] = {};
#pragma unroll
    for (int kt = 0; kt < nkt; kt++) {
        ushort8 a8 = *(const ushort8*)(aptr + kt * 32);
        const int kb = kt * 32 + koff;
        float4 s0 = *(const float4*)(scale + kb);
        float4 s1 = *(const float4*)(scale + kb + 4);
        float4 t0 = *(const float4*)(shift + kb);
        float4 t1 = *(const float4*)(shift + kb + 4);
        bf16x8 af;
        af[0] = (short)f2bf(fmaxf(s0.x * bf2f(a8[0]) + t0.x, 0.f));
        af[1] = (short)f2bf(fmaxf(s0.y * bf2f(a8[1]) + t0.y, 0.f));
        af[2] = (short)f2bf(fmaxf(s0.z * bf2f(a8[2]) + t0.z, 0.f));
        af[3] = (short)f2bf(fmaxf(s0.w * bf2f(a8[3]) + t0.w, 0.f));
        af[4] = (short)f2bf(fmaxf(s1.x * bf2f(a8[4]) + t1.x, 0.f));
        af[5] = (short)f2bf(fmaxf(s1.y * bf2f(a8[5]) + t1.y, 0.f));
        af[6] = (short)f2bf(fmaxf(s1.z * bf2f(a8[6]) + t1.z, 0.f));
        af[7] = (short)f2bf(fmaxf(s1.w * bf2f(a8[7]) + t1.w, 0.f));
#pragma unroll
        for (int nt = 0; nt < MT; nt++) {
            bf16x8 bfr = *(const bf16x8*)(Bp + (((size_t)nt * nkt + kt) * 64 + lane) * 8);
            acc[nt] = __builtin_amdgcn_mfma_f32_16x16x32_bf16(af, bfr, acc[nt], 0, 0, 0);
        }
    }
    const int rg = lane >> 4, cc = lane & 15;
#pragma unroll
    for (int nt = 0; nt < MT; nt++) {
        const int col = nt * 16 + cc;
        if (col < NCLS) {
            const size_t base = (size_t)(rowb + rg * 4) * NCLS + col;
#pragma unroll
            for (int i = 0; i < 4; i++) C[base + (size_t)i * NCLS] = acc[nt][i];
        }
    }
}

// ---------------- output: gather F=40 + bias + log_softmax, one wave/node ----
__global__ __launch_bounds__(256) void k_out(const float* __restrict__ XW,
                                             const int* __restrict__ rowp,
                                             const int* __restrict__ ssrc,
                                             const float* __restrict__ wnorm,
                                             const float* __restrict__ dinv,
                                             const float* __restrict__ bias,
                                             float* __restrict__ out) {
    const int wave = threadIdx.x >> 6;
    const int lane = threadIdx.x & 63;
    const int node = blockIdx.x * 4 + wave;
    const float dd = dinv[node];
    const bool act = lane < NCLS;
    float acc = 0.f;
    if (act) acc = dd * dd * XW[node * NCLS + lane];
    const int e0 = rowp[node], e1 = rowp[node + 1];
    int j = e0;
    for (; j + 3 < e1; j += 4) {
        const int i0 = ssrc[j], i1 = ssrc[j + 1], i2 = ssrc[j + 2], i3 = ssrc[j + 3];
        const float w0 = wnorm[j], w1 = wnorm[j + 1];
        const float w2 = wnorm[j + 2], w3 = wnorm[j + 3];
        float v0 = 0.f, v1 = 0.f, v2 = 0.f, v3 = 0.f;
        if (act) {
            v0 = XW[i0 * NCLS + lane]; v1 = XW[i1 * NCLS + lane];
            v2 = XW[i2 * NCLS + lane]; v3 = XW[i3 * NCLS + lane];
        }
        acc += w0 * v0 + w1 * v1 + w2 * v2 + w3 * v3;
    }
    for (; j < e1; j++) {
        const int s = ssrc[j];
        const float w = wnorm[j];
        if (act) acc += w * XW[s * NCLS + lane];
    }
    if (act) acc += bias[lane];
    float m = act ? acc : -1e30f;
#pragma unroll
    for (int off = 32; off > 0; off >>= 1) m = fmaxf(m, __shfl_xor(m, off));
    float e = act ? expf(acc - m) : 0.f;
#pragma unroll
    for (int off = 32; off > 0; off >>= 1) e += __shfl_xor(e, off);
    const float lse = m + logf(e);
    if (act) out[node * NCLS + lane] = acc - lse;
}

extern "C" void kernel_launch(void* const* d_in, const int* in_sizes, int n_in,
                              void* d_out, int out_size, void* d_ws, size_t ws_size,
                              hipStream_t stream) {
    const float* x   = (const float*)d_in[0];
    const int*   ei  = (const int*)d_in[1];
    const float* W1  = (const float*)d_in[2];
    const float* b1  = (const float*)d_in[3];
    const float* g1  = (const float*)d_in[4];
    const float* be1 = (const float*)d_in[5];
    const float* W2  = (const float*)d_in[6];
    const float* b2  = (const float*)d_in[7];
    const float* g2  = (const float*)d_in[8];
    const float* be2 = (const float*)d_in[9];
    const float* W3  = (const float*)d_in[10];
    const float* b3  = (const float*)d_in[11];
    float* out = (float*)d_out;

    const int* e_src = ei;
    const int* e_dst = ei + N_EDGES;

    // ---- workspace layout ----
    char* w = (char*)d_ws;
    unsigned short* Xb  = (unsigned short*)w;  w += (size_t)N_NODES * IN_FEAT * 2;  // 12.8 MB
    unsigned short* H1b = (unsigned short*)w;  w += (size_t)N_NODES * HIDDEN * 2;   // 25.6 MB
    unsigned short* H2b = (unsigned short*)w;  w += (size_t)N_NODES * HIDDEN * 2;   // 25.6 MB
    float* XW3    = (float*)w;                 w += (size_t)N_NODES * NCLS * 4;     // 8 MB
    float* bnp    = (float*)w;                 w += (size_t)GNB * 512 * 4;          // 6.4 MB
    float* bnp2   = (float*)w;                 w += (size_t)32 * 512 * 4;           // 64 KB
    float* dinv   = (float*)w;                 w += (size_t)N_NODES * 4;
    float* wnorm  = (float*)w;                 w += (size_t)N_EDGES * 4;            // 1.28 MB
    int*   counts = (int*)w;                   w += (size_t)N_NODES * 4;
    int*   rowp   = (int*)w;                   w += (size_t)(N_NODES + 4) * 4;
    int*   cursor = (int*)w;                   w += (size_t)N_NODES * 4;
    int*   ssrc   = (int*)w;                   w += (size_t)N_EDGES * 4;
    int*   partials=(int*)w;                   w += 256 * 4;
    float* scale1 = (float*)w;                 w += 256 * 4;
    float* shift1 = (float*)w;                 w += 256 * 4;
    float* scale2 = (float*)w;                 w += 256 * 4;
    float* shift2 = (float*)w;                 w += 256 * 4;
    unsigned short* W1p = (unsigned short*)w;  w += (size_t)16 * 4 * 64 * 8 * 2;    // 64 KB
    unsigned short* W2p = (unsigned short*)w;  w += (size_t)16 * 8 * 64 * 8 * 2;    // 128 KB
    unsigned short* W3p = (unsigned short*)w;  w += (size_t)3 * 8 * 64 * 8 * 2;     // 24 KB

    const int EB = (N_EDGES + 255) / 256;

    // ---- CSR build + prep (hist fused with cast/pack) ----
    hipMemsetAsync(counts, 0, (size_t)N_NODES * 4, stream);
    k_prep<<<PREP_HIST_NB + PREP_CVT_NB + PREP_PACK_NB, 256, 0, stream>>>(
        e_dst, counts, x, (ushort8*)Xb, W1, W2, W3, W1p, W2p, W3p);
    k_scan_local<<<SCAN_NB, SCAN_B, 0, stream>>>(counts, rowp, partials);
    k_scan_add<<<SCAN_NB, SCAN_B, 0, stream>>>(rowp, cursor, partials, counts, dinv);
    k_scatter<<<EB, 256, 0, stream>>>(e_src, e_dst, cursor, ssrc, dinv, wnorm);

    // ---- layer 1: fused (gather X -> MFMA W1 + b1 -> H1b, stats) ----
    k_fused<IN_FEAT, false><<<GNB, 256, 0, stream>>>(
        Xb, rowp, ssrc, wnorm, dinv, nullptr, nullptr, (const short*)W1p, b1, H1b, bnp);
    k_bnred<<<32, 512, 0, stream>>>(bnp, bnp2);
    k_bnprep<<<1, 256, 0, stream>>>(bnp2, g1, be1, scale1, shift1);

    // ---- layer 2: fused (gather relu(bn(H1)) -> MFMA W2 + b2 -> H2b, stats) --
    k_fused<HIDDEN, true><<<GNB, 256, 0, stream>>>(
        H1b, rowp, ssrc, wnorm, dinv, scale1, shift1, (const short*)W2p, b2, H2b, bnp);
    k_bnred<<<32, 512, 0, stream>>>(bnp, bnp2);
    k_bnprep<<<1, 256, 0, stream>>>(bnp2, g2, be2, scale2, shift2);

    // ---- output layer ----
    k_gemm3<HIDDEN><<<GNB, 64, 0, stream>>>(H2b, (const short*)W3p, scale2, shift2, XW3);
    k_out<<<N_NODES / 4, 256, 0, stream>>>(XW3, rowp, ssrc, wnorm, dinv, b3, out);
}

// Round 13
// 310.545 us; speedup vs baseline: 1.0239x; 1.0192x over previous
//
#include <hip/hip_runtime.h>

#define N_NODES 50000
#define N_EDGES 320000
#define IN_FEAT 128
#define HIDDEN  256
#define NCLS    40
#define BN_EPS  1e-5f

#define SCAN_B  256
#define SCAN_NB ((N_NODES + SCAN_B - 1) / SCAN_B)   // 196
#define GNB     (N_NODES / 16)                      // 3125 blocks, 16 nodes each

// prep kernel partition
#define PREP_HIST_NB  (N_EDGES / 256)               // 1250
#define PREP_CVT_NB   (N_NODES * IN_FEAT / 8 / 256) // 3125
#define PREP_PACK_NB  54                            // 216 wave-units / 4

typedef __attribute__((ext_vector_type(8))) _Float16 f16x8;
typedef __attribute__((ext_vector_type(2))) _Float16 f16x2;
typedef __attribute__((ext_vector_type(4))) float f32x4;

__device__ __forceinline__ f16x2 u2h(unsigned u) {
    union { unsigned u; f16x2 h; } c; c.u = u; return c.h;
}
__device__ __forceinline__ unsigned h2u(f16x2 h) {
    union { f16x2 h; unsigned u; } c; c.h = h; return c.u;
}
__device__ __forceinline__ f16x2 pkmax0(f16x2 a) {
    return __builtin_elementwise_max(a, (f16x2)(_Float16)0.f);
}

__device__ __forceinline__ void packB_unit(const float* __restrict__ W,
                                           _Float16* __restrict__ Bp,
                                           int nt, int kt, int nkt, int M, int lane) {
    const int n = nt * 16 + (lane & 15);
    const int kb = kt * 32 + (lane >> 4) * 8;
    _Float16* dst = Bp + (((size_t)nt * nkt + kt) * 64 + lane) * 8;
#pragma unroll
    for (int j = 0; j < 8; j++)
        dst[j] = (n < M) ? (_Float16)W[(size_t)(kb + j) * M + n] : (_Float16)0.f;
}

// ---------------- merged prep: hist + x cast + W packs ----------------
__global__ __launch_bounds__(256) void k_prep(const int* __restrict__ e_dst,
                                              int* __restrict__ counts,
                                              const float* __restrict__ x,
                                              _Float16* __restrict__ Xh,
                                              const float* __restrict__ W1,
                                              const float* __restrict__ W2,
                                              const float* __restrict__ W3,
                                              _Float16* __restrict__ W1p,
                                              _Float16* __restrict__ W2p,
                                              _Float16* __restrict__ W3p) {
    const int b = blockIdx.x;
    const int tid = threadIdx.x;
    if (b < PREP_HIST_NB) {
        const int e = b * 256 + tid;                  // 1250*256 == N_EDGES
        atomicAdd(&counts[e_dst[e]], 1);
    } else if (b < PREP_HIST_NB + PREP_CVT_NB) {
        const int i = (b - PREP_HIST_NB) * 256 + tid; // exact cover
        float4 a = *(const float4*)(x + (size_t)i * 8);
        float4 c = *(const float4*)(x + (size_t)i * 8 + 4);
        f16x8 o = {(_Float16)a.x, (_Float16)a.y, (_Float16)a.z, (_Float16)a.w,
                   (_Float16)c.x, (_Float16)c.y, (_Float16)c.z, (_Float16)c.w};
        *(f16x8*)&Xh[(size_t)i * 8] = o;
    } else {
        const int wave = tid >> 6, lane = tid & 63;
        const int u = (b - PREP_HIST_NB - PREP_CVT_NB) * 4 + wave;  // 0..215
        if (u < 64) {
            packB_unit(W1, W1p, u >> 2, u & 3, 4, HIDDEN, lane);
        } else if (u < 192) {
            const int v = u - 64;
            packB_unit(W2, W2p, v >> 3, v & 7, 8, HIDDEN, lane);
        } else {
            const int v = u - 192;
            packB_unit(W3, W3p, v >> 3, v & 7, 8, NCLS, lane);
        }
    }
}

// ---------------- CSR scan ----------------
__global__ __launch_bounds__(SCAN_B) void k_scan_local(const int* __restrict__ counts,
                                                       int* __restrict__ rowp,
                                                       int* __restrict__ partials) {
    __shared__ int s[SCAN_B];
    const int tid = threadIdx.x;
    const int i = blockIdx.x * SCAN_B + tid;
    int v = (i < N_NODES) ? counts[i] : 0;
    s[tid] = v;
    __syncthreads();
    for (int off = 1; off < SCAN_B; off <<= 1) {
        int t = (tid >= off) ? s[tid - off] : 0;
        __syncthreads();
        s[tid] += t;
        __syncthreads();
    }
    if (i < N_NODES) rowp[i] = s[tid] - v;
    if (tid == SCAN_B - 1) partials[blockIdx.x] = s[SCAN_B - 1];
}

__global__ __launch_bounds__(SCAN_B) void k_scan_add(int* __restrict__ rowp,
                                                     int* __restrict__ cursor,
                                                     const int* __restrict__ partials,
                                                     const int* __restrict__ counts,
                                                     float* __restrict__ dinv) {
    __shared__ int s[SCAN_B];
    const int tid = threadIdx.x;
    const int b = blockIdx.x;
    int v = (tid < b) ? partials[tid] : 0;
    s[tid] = v;
    __syncthreads();
    for (int off = SCAN_B / 2; off > 0; off >>= 1) {
        if (tid < off) s[tid] += s[tid + off];
        __syncthreads();
    }
    const int offset = s[0];
    const int i = b * SCAN_B + tid;
    if (i < N_NODES) {
        int r = rowp[i] + offset;
        rowp[i] = r;
        cursor[i] = r;
        dinv[i] = rsqrtf(1.0f + (float)counts[i]);
    }
    if (b == 0 && tid == 0) rowp[N_NODES] = N_EDGES;
}

// scatter + per-edge normalized weight
__global__ void k_scatter(const int* __restrict__ src, const int* __restrict__ dst,
                          int* __restrict__ cursor, int* __restrict__ ssrc,
                          const float* __restrict__ dinv, float* __restrict__ wnorm) {
    int e = blockIdx.x * blockDim.x + threadIdx.x;
    if (e < N_EDGES) {
        int d = dst[e], s = src[e];
        int p = atomicAdd(&cursor[d], 1);
        ssrc[p] = s;
        wnorm[p] = dinv[s] * dinv[d];
    }
}

// ---------------- fused layer: gather (packed-half) -> LDS -> MFMA f16 --------
// Block: 16 nodes (4/wave, sequential per node — R9 shape). Packed f16x2 math.
template <int KIN, bool BN>
__global__ __launch_bounds__(256) void k_fused(const _Float16* __restrict__ Xin,
                                               const int* __restrict__ rowp,
                                               const int* __restrict__ ssrc,
                                               const float* __restrict__ wnorm,
                                               const float* __restrict__ dinv,
                                               const float* __restrict__ scale,
                                               const float* __restrict__ shift,
                                               const _Float16* __restrict__ Bp,
                                               const float* __restrict__ bias,
                                               _Float16* __restrict__ C,
                                               float* __restrict__ bnp) {
    constexpr int nkt = KIN / 32;
    constexpr int LROW = KIN + 8;
    __shared__ __align__(16) _Float16 At[16 * LROW];
    const int wave = threadIdx.x >> 6;
    const int lane = threadIdx.x & 63;
    const int node0 = blockIdx.x * 16 + wave * 4;

    if constexpr (KIN == 128) {
        const unsigned* Xu = (const unsigned*)Xin;   // lane = 2 feats
#pragma unroll
        for (int nn = 0; nn < 4; nn++) {
            const int node = node0 + nn;
            const float dd = dinv[node];
            const f16x2 sw2 = (f16x2)(_Float16)(dd * dd);
            f16x2 a0 = sw2 * u2h(Xu[(size_t)node * 64 + lane]);
            const int e0 = rowp[node], e1 = rowp[node + 1];
            int j = e0;
            for (; j + 3 < e1; j += 4) {
                const int i0 = ssrc[j], i1 = ssrc[j + 1], i2 = ssrc[j + 2], i3 = ssrc[j + 3];
                const f16x2 w0 = (f16x2)(_Float16)wnorm[j];
                const f16x2 w1 = (f16x2)(_Float16)wnorm[j + 1];
                const f16x2 w2 = (f16x2)(_Float16)wnorm[j + 2];
                const f16x2 w3 = (f16x2)(_Float16)wnorm[j + 3];
                const f16x2 u0 = u2h(Xu[(size_t)i0 * 64 + lane]);
                const f16x2 u1 = u2h(Xu[(size_t)i1 * 64 + lane]);
                const f16x2 u2 = u2h(Xu[(size_t)i2 * 64 + lane]);
                const f16x2 u3 = u2h(Xu[(size_t)i3 * 64 + lane]);
                a0 = w0 * u0 + a0;
                a0 = w1 * u1 + a0;
                a0 = w2 * u2 + a0;
                a0 = w3 * u3 + a0;
            }
            for (; j < e1; j++) {
                const f16x2 w = (f16x2)(_Float16)wnorm[j];
                a0 = w * u2h(Xu[(size_t)ssrc[j] * 64 + lane]) + a0;
            }
            *(f16x2*)&At[(wave * 4 + nn) * LROW + lane * 2] = a0;
        }
    } else {
        const uint2* Xu = (const uint2*)Xin;       // lane = 4 feats
        f16x2 sc01 = (f16x2)(_Float16)0.f, sc23 = sc01, sh01 = sc01, sh23 = sc01;
        if constexpr (BN) {
            const int f = lane * 4;
            sc01 = f16x2{(_Float16)scale[f], (_Float16)scale[f + 1]};
            sc23 = f16x2{(_Float16)scale[f + 2], (_Float16)scale[f + 3]};
            sh01 = f16x2{(_Float16)shift[f], (_Float16)shift[f + 1]};
            sh23 = f16x2{(_Float16)shift[f + 2], (_Float16)shift[f + 3]};
        }
#pragma unroll
        for (int nn = 0; nn < 4; nn++) {
            const int node = node0 + nn;
            const float dd = dinv[node];
            const f16x2 sw2 = (f16x2)(_Float16)(dd * dd);
            uint2 raw = Xu[(size_t)node * 64 + lane];
            f16x2 a0 = sw2 * pkmax0(sc01 * u2h(raw.x) + sh01);
            f16x2 a1 = sw2 * pkmax0(sc23 * u2h(raw.y) + sh23);
            const int e0 = rowp[node], e1 = rowp[node + 1];
            int j = e0;
            for (; j + 3 < e1; j += 4) {
                const int i0 = ssrc[j], i1 = ssrc[j + 1], i2 = ssrc[j + 2], i3 = ssrc[j + 3];
                const f16x2 w0 = (f16x2)(_Float16)wnorm[j];
                const f16x2 w1 = (f16x2)(_Float16)wnorm[j + 1];
                const f16x2 w2 = (f16x2)(_Float16)wnorm[j + 2];
                const f16x2 w3 = (f16x2)(_Float16)wnorm[j + 3];
                const uint2 r0 = Xu[(size_t)i0 * 64 + lane];
                const uint2 r1 = Xu[(size_t)i1 * 64 + lane];
                const uint2 r2 = Xu[(size_t)i2 * 64 + lane];
                const uint2 r3 = Xu[(size_t)i3 * 64 + lane];
                a0 = w0 * pkmax0(sc01 * u2h(r0.x) + sh01) + a0;
                a1 = w0 * pkmax0(sc23 * u2h(r0.y) + sh23) + a1;
                a0 = w1 * pkmax0(sc01 * u2h(r1.x) + sh01) + a0;
                a1 = w1 * pkmax0(sc23 * u2h(r1.y) + sh23) + a1;
                a0 = w2 * pkmax0(sc01 * u2h(r2.x) + sh01) + a0;
                a1 = w2 * pkmax0(sc23 * u2h(r2.y) + sh23) + a1;
                a0 = w3 * pkmax0(sc01 * u2h(r3.x) + sh01) + a0;
                a1 = w3 * pkmax0(sc23 * u2h(r3.y) + sh23) + a1;
            }
            for (; j < e1; j++) {
                const f16x2 w = (f16x2)(_Float16)wnorm[j];
                const uint2 r = Xu[(size_t)ssrc[j] * 64 + lane];
                a0 = w * pkmax0(sc01 * u2h(r.x) + sh01) + a0;
                a1 = w * pkmax0(sc23 * u2h(r.y) + sh23) + a1;
            }
            uint2 o; o.x = h2u(a0); o.y = h2u(a1);
            *(uint2*)&At[(wave * 4 + nn) * LROW + lane * 4] = o;
        }
    }
    __syncthreads();

    // ---- phase 2: MFMA f16 ----
    const int rowb = blockIdx.x * 16;
    const int ntile0 = wave * 4;
    const _Float16* aL = &At[(lane & 15) * LROW + (lane >> 4) * 8];
    f32x4 acc[4] = {};
#pragma unroll
    for (int kt = 0; kt < nkt; kt++) {
        f16x8 af = *(const f16x8*)(aL + kt * 32);
#pragma unroll
        for (int nt = 0; nt < 4; nt++) {
            f16x8 bfr = *(const f16x8*)(Bp + (((size_t)(ntile0 + nt) * nkt + kt) * 64 + lane) * 8);
            acc[nt] = __builtin_amdgcn_mfma_f32_16x16x32_f16(af, bfr, acc[nt], 0, 0, 0);
        }
    }
    const int rg = lane >> 4, cc = lane & 15;    // C/D: col=lane&15, row=rg*4+i
    float s[4], q2[4];
#pragma unroll
    for (int nt = 0; nt < 4; nt++) {
        const int col = (ntile0 + nt) * 16 + cc;
        const float b = bias[col];
        f32x4 a = acc[nt];
        a[0] += b; a[1] += b; a[2] += b; a[3] += b;
        const size_t base = (size_t)(rowb + rg * 4) * HIDDEN + col;
#pragma unroll
        for (int i = 0; i < 4; i++) C[base + (size_t)i * HIDDEN] = (_Float16)a[i];
        s[nt] = a[0] + a[1] + a[2] + a[3];
        q2[nt] = a[0]*a[0] + a[1]*a[1] + a[2]*a[2] + a[3]*a[3];
    }
#pragma unroll
    for (int nt = 0; nt < 4; nt++) {
        s[nt] += __shfl_xor(s[nt], 16); s[nt] += __shfl_xor(s[nt], 32);
        q2[nt] += __shfl_xor(q2[nt], 16); q2[nt] += __shfl_xor(q2[nt], 32);
    }
    if (lane < 16) {
        float* dst = bnp + (size_t)blockIdx.x * 512 + ntile0 * 16 + lane;
#pragma unroll
        for (int nt = 0; nt < 4; nt++) {
            dst[nt * 16]       = s[nt];
            dst[nt * 16 + 256] = q2[nt];
        }
    }
}

// ---------------- BN partial reduce: bnp[GNB][512] -> bnp2[32][512] ----------
__global__ __launch_bounds__(512) void k_bnred(const float* __restrict__ bnp,
                                               float* __restrict__ bnp2) {
    const int t = threadIdx.x;
    const int b = blockIdx.x;                  // 32
    const int per = (GNB + 31) / 32;           // 98
    int r0 = b * per, r1 = r0 + per; if (r1 > GNB) r1 = GNB;
    float s = 0.f;
    for (int r = r0; r < r1; r++) s += bnp[(size_t)r * 512 + t];
    bnp2[(size_t)b * 512 + t] = s;
}

// ---------------- BN prep: bnp2 -> scale/shift ----------------
__global__ __launch_bounds__(256) void k_bnprep(const float* __restrict__ bnp2,
                                                const float* __restrict__ g,
                                                const float* __restrict__ be,
                                                float* __restrict__ scale,
                                                float* __restrict__ shift) {
    const int f = threadIdx.x;
    float s = 0.f, q = 0.f;
#pragma unroll
    for (int b = 0; b < 32; b++) {
        s += bnp2[(size_t)b * 512 + f];
        q += bnp2[(size_t)b * 512 + 256 + f];
    }
    const float inv_n = 1.0f / (float)N_NODES;
    float mean = s * inv_n;
    float var = q * inv_n - mean * mean;
    var = fmaxf(var, 0.f);
    float sc = g[f] * rsqrtf(var + BN_EPS);
    scale[f] = sc;
    shift[f] = be[f] - mean * sc;
}

// ---------------- GEMM3: XW3 = relu(bn(H2)) @ W3, fp32 out, 1 wave MT=3 ------
template <int K_>
__global__ __launch_bounds__(64) void k_gemm3(const _Float16* __restrict__ A,
                                              const _Float16* __restrict__ Bp,
                                              const float* __restrict__ scale,
                                              const float* __restrict__ shift,
                                              float* __restrict__ C) {
    constexpr int nkt = K_ / 32;
    constexpr int MT = 3;
    const int lane = threadIdx.x & 63;
    const int rowb = blockIdx.x * 16;
    const int koff = (lane >> 4) * 8;
    const _Float16* aptr = A + (size_t)(rowb + (lane & 15)) * K_ + koff;
    f32x4 acc[MT] = {};
#pragma unroll
    for (int kt = 0; kt < nkt; kt++) {
        union { f16x8 v; f16x2 h[4]; } au, tu;
        au.v = *(const f16x8*)(aptr + kt * 32);
        const int kb = kt * 32 + koff;
#pragma unroll
        for (int p = 0; p < 4; p++) {
            f16x2 sc2 = {(_Float16)scale[kb + 2 * p], (_Float16)scale[kb + 2 * p + 1]};
            f16x2 sh2 = {(_Float16)shift[kb + 2 * p], (_Float16)shift[kb + 2 * p + 1]};
            tu.h[p] = pkmax0(sc2 * au.h[p] + sh2);
        }
#pragma unroll
        for (int nt = 0; nt < MT; nt++) {
            f16x8 bfr = *(const f16x8*)(Bp + (((size_t)nt * nkt + kt) * 64 + lane) * 8);
            acc[nt] = __builtin_amdgcn_mfma_f32_16x16x32_f16(tu.v, bfr, acc[nt], 0, 0, 0);
        }
    }
    const int rg = lane >> 4, cc = lane & 15;
#pragma unroll
    for (int nt = 0; nt < MT; nt++) {
        const int col = nt * 16 + cc;
        if (col < NCLS) {
            const size_t base = (size_t)(rowb + rg * 4) * NCLS + col;
#pragma unroll
            for (int i = 0; i < 4; i++) C[base + (size_t)i * NCLS] = acc[nt][i];
        }
    }
}

// ---------------- output: gather F=40 + bias + log_softmax, one wave/node ----
__global__ __launch_bounds__(256) void k_out(const float* __restrict__ XW,
                                             const int* __restrict__ rowp,
                                             const int* __restrict__ ssrc,
                                             const float* __restrict__ wnorm,
                                             const float* __restrict__ dinv,
                                             const float* __restrict__ bias,
                                             float* __restrict__ out) {
    const int wave = threadIdx.x >> 6;
    const int lane = threadIdx.x & 63;
    const int node = blockIdx.x * 4 + wave;
    const float dd = dinv[node];
    const bool act = lane < NCLS;
    float acc = 0.f;
    if (act) acc = dd * dd * XW[node * NCLS + lane];
    const int e0 = rowp[node], e1 = rowp[node + 1];
    int j = e0;
    for (; j + 3 < e1; j += 4) {
        const int i0 = ssrc[j], i1 = ssrc[j + 1], i2 = ssrc[j + 2], i3 = ssrc[j + 3];
        const float w0 = wnorm[j], w1 = wnorm[j + 1];
        const float w2 = wnorm[j + 2], w3 = wnorm[j + 3];
        float v0 = 0.f, v1 = 0.f, v2 = 0.f, v3 = 0.f;
        if (act) {
            v0 = XW[i0 * NCLS + lane]; v1 = XW[i1 * NCLS + lane];
            v2 = XW[i2 * NCLS + lane]; v3 = XW[i3 * NCLS + lane];
        }
        acc += w0 * v0 + w1 * v1 + w2 * v2 + w3 * v3;
    }
    for (; j < e1; j++) {
        const int s = ssrc[j];
        const float w = wnorm[j];
        if (act) acc += w * XW[s * NCLS + lane];
    }
    if (act) acc += bias[lane];
    float m = act ? acc : -1e30f;
#pragma unroll
    for (int off = 32; off > 0; off >>= 1) m = fmaxf(m, __shfl_xor(m, off));
    float e = act ? expf(acc - m) : 0.f;
#pragma unroll
    for (int off = 32; off > 0; off >>= 1) e += __shfl_xor(e, off);
    const float lse = m + logf(e);
    if (act) out[node * NCLS + lane] = acc - lse;
}

extern "C" void kernel_launch(void* const* d_in, const int* in_sizes, int n_in,
                              void* d_out, int out_size, void* d_ws, size_t ws_size,
                              hipStream_t stream) {
    const float* x   = (const float*)d_in[0];
    const int*   ei  = (const int*)d_in[1];
    const float* W1  = (const float*)d_in[2];
    const float* b1  = (const float*)d_in[3];
    const float* g1  = (const float*)d_in[4];
    const float* be1 = (const float*)d_in[5];
    const float* W2  = (const float*)d_in[6];
    const float* b2  = (const float*)d_in[7];
    const float* g2  = (const float*)d_in[8];
    const float* be2 = (const float*)d_in[9];
    const float* W3  = (const float*)d_in[10];
    const float* b3  = (const float*)d_in[11];
    float* out = (float*)d_out;

    const int* e_src = ei;
    const int* e_dst = ei + N_EDGES;

    // ---- workspace layout ----
    char* w = (char*)d_ws;
    _Float16* Xh  = (_Float16*)w;              w += (size_t)N_NODES * IN_FEAT * 2;  // 12.8 MB
    _Float16* H1h = (_Float16*)w;              w += (size_t)N_NODES * HIDDEN * 2;   // 25.6 MB
    _Float16* H2h = (_Float16*)w;              w += (size_t)N_NODES * HIDDEN * 2;   // 25.6 MB
    float* XW3    = (float*)w;                 w += (size_t)N_NODES * NCLS * 4;     // 8 MB
    float* bnp    = (float*)w;                 w += (size_t)GNB * 512 * 4;          // 6.4 MB
    float* bnp2   = (float*)w;                 w += (size_t)32 * 512 * 4;           // 64 KB
    float* dinv   = (float*)w;                 w += (size_t)N_NODES * 4;
    float* wnorm  = (float*)w;                 w += (size_t)N_EDGES * 4;            // 1.28 MB
    int*   counts = (int*)w;                   w += (size_t)N_NODES * 4;
    int*   rowp   = (int*)w;                   w += (size_t)(N_NODES + 4) * 4;
    int*   cursor = (int*)w;                   w += (size_t)N_NODES * 4;
    int*   ssrc   = (int*)w;                   w += (size_t)N_EDGES * 4;
    int*   partials=(int*)w;                   w += 256 * 4;
    float* scale1 = (float*)w;                 w += 256 * 4;
    float* shift1 = (float*)w;                 w += 256 * 4;
    float* scale2 = (float*)w;                 w += 256 * 4;
    float* shift2 = (float*)w;                 w += 256 * 4;
    _Float16* W1p = (_Float16*)w;              w += (size_t)16 * 4 * 64 * 8 * 2;    // 64 KB
    _Float16* W2p = (_Float16*)w;              w += (size_t)16 * 8 * 64 * 8 * 2;    // 128 KB
    _Float16* W3p = (_Float16*)w;              w += (size_t)3 * 8 * 64 * 8 * 2;     // 24 KB

    const int EB = (N_EDGES + 255) / 256;

    // ---- CSR build + prep (hist fused with cast/pack) ----
    hipMemsetAsync(counts, 0, (size_t)N_NODES * 4, stream);
    k_prep<<<PREP_HIST_NB + PREP_CVT_NB + PREP_PACK_NB, 256, 0, stream>>>(
        e_dst, counts, x, Xh, W1, W2, W3, W1p, W2p, W3p);
    k_scan_local<<<SCAN_NB, SCAN_B, 0, stream>>>(counts, rowp, partials);
    k_scan_add<<<SCAN_NB, SCAN_B, 0, stream>>>(rowp, cursor, partials, counts, dinv);
    k_scatter<<<EB, 256, 0, stream>>>(e_src, e_dst, cursor, ssrc, dinv, wnorm);

    // ---- layer 1: fused (gather X -> MFMA W1 + b1 -> H1h, stats) ----
    k_fused<IN_FEAT, false><<<GNB, 256, 0, stream>>>(
        Xh, rowp, ssrc, wnorm, dinv, nullptr, nullptr, W1p, b1, H1h, bnp);
    k_bnred<<<32, 512, 0, stream>>>(bnp, bnp2);
    k_bnprep<<<1, 256, 0, stream>>>(bnp2, g1, be1, scale1, shift1);

    // ---- layer 2: fused (gather relu(bn(H1)) -> MFMA W2 + b2 -> H2h, stats) --
    k_fused<HIDDEN, true><<<GNB, 256, 0, stream>>>(
        H1h, rowp, ssrc, wnorm, dinv, scale1, shift1, W2p, b2, H2h, bnp);
    k_bnred<<<32, 512, 0, stream>>>(bnp, bnp2);
    k_bnprep<<<1, 256, 0, stream>>>(bnp2, g2, be2, scale2, shift2);

    // ---- output layer ----
    k_gemm3<HIDDEN><<<GNB, 64, 0, stream>>>(H2h, W3p, scale2, shift2, XW3);
    k_out<<<N_NODES / 4, 256, 0, stream>>>(XW3, rowp, ssrc, wnorm, dinv, b3, out);
}